// Round 1
// baseline (444.146 us; speedup 1.0000x reference)
//
#include <hip/hip_runtime.h>
#include <math.h>

// Problem constants
#define SEQ   2048
#define NHEAD 8
#define CDIM  32

// ---------------------------------------------------------------------------
// Tiled f32 GEMM: C[M,N] = A[M,K=256] @ W[256,N] + bvec[N], fused epilogue.
// BM=64, BN=64, BK=16, 256 threads, 4x4 per-thread tile.
// MODE 0: QG proj -> out0 = q*scale [h][s][32], out1 = sigmoid(g) [h][s][32]
// MODE 1: KV proj -> out0 = k,       out1 = v
// MODE 2: O  proj -> out0[m*256+n] = v   (final output)
// ---------------------------------------------------------------------------
template<int MODE>
__global__ __launch_bounds__(256)
void proj_kernel(const float* __restrict__ A, const float* __restrict__ W,
                 const float* __restrict__ bvec, float* __restrict__ out0,
                 float* __restrict__ out1, int N)
{
    const int K = 256;
    __shared__ float As[16][64];   // [k][m] (transposed for stride-1 over m)
    __shared__ float Bs[16][64];   // [k][n]

    const int tid = threadIdx.x;
    const int tx  = tid & 15;      // n-group
    const int ty  = tid >> 4;      // m-group
    const int m0  = blockIdx.x * 64;
    const int n0  = blockIdx.y * 64;

    const int arow = tid >> 2;           // 0..63
    const int acol = (tid & 3) << 2;     // 0,4,8,12
    const int brow = tid >> 4;           // 0..15
    const int bcol = (tid & 15) << 2;    // 0..60

    float acc[4][4] = {};
    for (int k0 = 0; k0 < K; k0 += 16) {
        float4 a4 = *(const float4*)(A + (size_t)(m0 + arow) * K + k0 + acol);
        float4 b4 = *(const float4*)(W + (size_t)(k0 + brow) * N + n0 + bcol);
        __syncthreads();
        As[acol + 0][arow] = a4.x;
        As[acol + 1][arow] = a4.y;
        As[acol + 2][arow] = a4.z;
        As[acol + 3][arow] = a4.w;
        *(float4*)&Bs[brow][bcol] = b4;
        __syncthreads();
#pragma unroll
        for (int kk = 0; kk < 16; kk++) {
            float av[4], bv[4];
            *(float4*)av = *(const float4*)&As[kk][ty << 2];
            *(float4*)bv = *(const float4*)&Bs[kk][tx << 2];
#pragma unroll
            for (int i = 0; i < 4; i++)
#pragma unroll
                for (int j = 0; j < 4; j++)
                    acc[i][j] = fmaf(av[i], bv[j], acc[i][j]);
        }
    }

    const float scale = 0.17677669529663689f;  // 32^-0.5
#pragma unroll
    for (int i = 0; i < 4; i++) {
        const int m = m0 + (ty << 2) + i;
#pragma unroll
        for (int j = 0; j < 4; j++) {
            const int nc = (tx << 2) + j;        // 0..63 within tile
            const int n  = n0 + nc;
            float v = acc[i][j] + bvec[n];
            if (MODE == 0) {
                const int h = blockIdx.y;        // N=512: one head per n-tile
                if (nc < 32)
                    out0[((((size_t)h << 11) + m) << 5) + nc] = v * scale;
                else
                    out1[((((size_t)h << 11) + m) << 5) + (nc - 32)] =
                        1.0f / (1.0f + __expf(-v));
            } else if (MODE == 1) {
                const int h = blockIdx.y;
                if (nc < 32)
                    out0[((((size_t)h << 11) + m) << 5) + nc] = v;
                else
                    out1[((((size_t)h << 11) + m) << 5) + (nc - 32)] = v;
            } else {
                out0[(size_t)m * 256 + n] = v;
            }
        }
    }
}

// ---------------------------------------------------------------------------
// Flash attention: one block per (head, 64 q-rows). Nk=64 k-tiles.
// Online softmax; bias streamed straight to registers (dominant HBM traffic);
// K/V staged transposed in LDS with pad-68 rows (16B-aligned b128 reads).
// Epilogue fuses 1/l, sigmoid-gating, and stores att[q][h*32+c].
// ---------------------------------------------------------------------------
__global__ __launch_bounds__(256)
void attn_kernel(const float* __restrict__ qs, const float* __restrict__ gs,
                 const float* __restrict__ ks, const float* __restrict__ vs,
                 const float* __restrict__ bias, float* __restrict__ att)
{
    const int h   = blockIdx.y;
    const int q0  = blockIdx.x * 64;
    const int tid = threadIdx.x;
    const int lg16 = tid & 15;      // k-group (logits) / c-group (PV)
    const int qg   = tid >> 4;      // q-group: 16 groups x 4 rows
    const int qr0  = qg << 2;

    __shared__ float Qt[32][68];    // [c][qr]
    __shared__ float Kt[32][68];    // [c][kk]
    __shared__ float Vt[32][68];    // [c][kk]
    __shared__ float Ps[64][68];    // [qr][kk]

    // Stage Q (already scaled by C^-0.5)
#pragma unroll
    for (int r = 0; r < 2; r++) {
        const int f  = tid + (r << 8);
        const int qr = f >> 3;
        const int c0 = (f & 7) << 2;
        float4 v = *(const float4*)(qs + ((((size_t)h << 11) + q0 + qr) << 5) + c0);
        Qt[c0 + 0][qr] = v.x; Qt[c0 + 1][qr] = v.y;
        Qt[c0 + 2][qr] = v.z; Qt[c0 + 3][qr] = v.w;
    }

    float mrow[4], lrow[4], Ob[4][2];
#pragma unroll
    for (int i = 0; i < 4; i++) {
        mrow[i] = -1e30f; lrow[i] = 0.f; Ob[i][0] = 0.f; Ob[i][1] = 0.f;
    }

    const size_t bias_base = (((size_t)h) * SEQ + q0) * SEQ;
    const int c0v = lg16 << 1;   // PV: this thread's 2 c-columns

    for (int kt = 0; kt < 32; kt++) {
        const int k0 = kt << 6;

        // Prefetch bias tile into registers BEFORE the barrier (hides latency)
        float br[4][4];
#pragma unroll
        for (int i = 0; i < 4; i++) {
            float4 b4 = *(const float4*)(bias + bias_base + (size_t)(qr0 + i) * SEQ
                                         + k0 + (lg16 << 2));
            br[i][0] = b4.x; br[i][1] = b4.y; br[i][2] = b4.z; br[i][3] = b4.w;
        }

        __syncthreads();   // previous PV done reading Kt/Vt; Qt ready (iter 0)
        // Stage K, V tiles transposed
#pragma unroll
        for (int r = 0; r < 2; r++) {
            const int f  = tid + (r << 8);
            const int kk = f >> 3;
            const int cc = (f & 7) << 2;
            float4 k4 = *(const float4*)(ks + ((((size_t)h << 11) + k0 + kk) << 5) + cc);
            Kt[cc + 0][kk] = k4.x; Kt[cc + 1][kk] = k4.y;
            Kt[cc + 2][kk] = k4.z; Kt[cc + 3][kk] = k4.w;
            float4 v4 = *(const float4*)(vs + ((((size_t)h << 11) + k0 + kk) << 5) + cc);
            Vt[cc + 0][kk] = v4.x; Vt[cc + 1][kk] = v4.y;
            Vt[cc + 2][kk] = v4.z; Vt[cc + 3][kk] = v4.w;
        }
        __syncthreads();

        // Logits: 4q x 4k per thread
        float lgt[4][4];
#pragma unroll
        for (int i = 0; i < 4; i++)
#pragma unroll
            for (int j = 0; j < 4; j++) lgt[i][j] = br[i][j];
#pragma unroll
        for (int c = 0; c < 32; c++) {
            float qa[4], ka[4];
            *(float4*)qa = *(const float4*)&Qt[c][qr0];
            *(float4*)ka = *(const float4*)&Kt[c][lg16 << 2];
#pragma unroll
            for (int i = 0; i < 4; i++)
#pragma unroll
                for (int j = 0; j < 4; j++)
                    lgt[i][j] = fmaf(qa[i], ka[j], lgt[i][j]);
        }

        // Online softmax per q-row (reduced over the 16 lanes sharing qg)
        float alpha[4];
#pragma unroll
        for (int i = 0; i < 4; i++) {
            float rm = fmaxf(fmaxf(lgt[i][0], lgt[i][1]),
                             fmaxf(lgt[i][2], lgt[i][3]));
#pragma unroll
            for (int off = 1; off < 16; off <<= 1)
                rm = fmaxf(rm, __shfl_xor(rm, off, 16));
            const float mnew = fmaxf(mrow[i], rm);
            alpha[i] = __expf(mrow[i] - mnew);
            mrow[i]  = mnew;
            float rs = 0.f;
#pragma unroll
            for (int j = 0; j < 4; j++) {
                const float p = __expf(lgt[i][j] - mnew);
                lgt[i][j] = p;
                rs += p;
            }
#pragma unroll
            for (int off = 1; off < 16; off <<= 1)
                rs += __shfl_xor(rs, off, 16);
            lrow[i] = lrow[i] * alpha[i] + rs;
            *(float4*)&Ps[qr0 + i][lg16 << 2] = *(float4*)lgt[i];
        }
        __syncthreads();   // Ps visible to the whole block

        // PV: O[4q][2c] += P @ V^T
#pragma unroll
        for (int i = 0; i < 4; i++) { Ob[i][0] *= alpha[i]; Ob[i][1] *= alpha[i]; }
#pragma unroll
        for (int k4 = 0; k4 < 16; k4++) {
            float pa[4][4], va[2][4];
#pragma unroll
            for (int i = 0; i < 4; i++)
                *(float4*)pa[i] = *(const float4*)&Ps[qr0 + i][k4 << 2];
#pragma unroll
            for (int j = 0; j < 2; j++)
                *(float4*)va[j] = *(const float4*)&Vt[c0v + j][k4 << 2];
#pragma unroll
            for (int i = 0; i < 4; i++)
#pragma unroll
                for (int j = 0; j < 2; j++)
#pragma unroll
                    for (int t = 0; t < 4; t++)
                        Ob[i][j] = fmaf(pa[i][t], va[j][t], Ob[i][j]);
        }
    }

    // Epilogue: 1/l, sigmoid gate, store att[q][h*32+c]
#pragma unroll
    for (int i = 0; i < 4; i++) {
        const int q = q0 + qr0 + i;
        const float inv = 1.0f / lrow[i];
#pragma unroll
        for (int j = 0; j < 2; j++) {
            const int c = c0v + j;
            const float g = gs[((((size_t)h << 11) + q) << 5) + c];
            att[(size_t)q * 256 + h * CDIM + c] = Ob[i][j] * inv * g;
        }
    }
}

// ---------------------------------------------------------------------------
extern "C" void kernel_launch(void* const* d_in, const int* in_sizes, int n_in,
                              void* d_out, int out_size, void* d_ws, size_t ws_size,
                              hipStream_t stream)
{
    const float* q_in  = (const float*)d_in[0];
    const float* kv_in = (const float*)d_in[1];
    const float* bias  = (const float*)d_in[2];
    const float* qg_w  = (const float*)d_in[3];
    const float* kv_w  = (const float*)d_in[4];
    const float* qg_b  = (const float*)d_in[5];
    const float* kv_b  = (const float*)d_in[6];
    const float* o_w   = (const float*)d_in[7];
    const float* o_b   = (const float*)d_in[8];
    float* out = (float*)d_out;

    float* ws  = (float*)d_ws;
    const size_t per = (size_t)NHEAD * SEQ * CDIM;   // 524288 floats
    float* qs  = ws;             // scaled q   [h][s][32]
    float* gs  = qs + per;       // sigmoid(g) [h][s][32]
    float* ks  = gs + per;       // k          [h][s][32]
    float* vs  = ks + per;       // v          [h][s][32]
    float* att = vs + per;       // gated attn_out [s][h*32+c]

    hipLaunchKernelGGL((proj_kernel<0>), dim3(32, 8), dim3(256), 0, stream,
                       q_in, qg_w, qg_b, qs, gs, 512);
    hipLaunchKernelGGL((proj_kernel<1>), dim3(32, 8), dim3(256), 0, stream,
                       kv_in, kv_w, kv_b, ks, vs, 512);
    hipLaunchKernelGGL((attn_kernel), dim3(32, 8), dim3(256), 0, stream,
                       qs, gs, ks, vs, bias, att);
    hipLaunchKernelGGL((proj_kernel<2>), dim3(32, 4), dim3(256), 0, stream,
                       att, o_w, o_b, out, (float*)nullptr, 256);
}

// Round 2
// 325.004 us; speedup vs baseline: 1.3666x; 1.3666x over previous
//
#include <hip/hip_runtime.h>
#include <math.h>

#define SEQ   2048
#define NHEAD 8
#define CDIM  32

// ---------------------------------------------------------------------------
// Fused QG + KV projection. z=0: QG (out qs = q*scale, gs = sigmoid(g));
// z=1: KV (out ks, vs). C[M=2048, N=512] = A[M,256] @ W[256,512] + b.
// BM=32, BN=64, BK=16, 256 threads, per-thread 2x4. grid (64, 8, 2).
// ---------------------------------------------------------------------------
__global__ __launch_bounds__(256)
void proj_qgkv_kernel(const float* __restrict__ q_in, const float* __restrict__ kv_in,
                      const float* __restrict__ qg_w, const float* __restrict__ kv_w,
                      const float* __restrict__ qg_b, const float* __restrict__ kv_b,
                      float* __restrict__ qs, float* __restrict__ gs,
                      float* __restrict__ ks, float* __restrict__ vs)
{
    const int z = blockIdx.z;
    const float* __restrict__ A  = z ? kv_in : q_in;
    const float* __restrict__ W  = z ? kv_w  : qg_w;
    const float* __restrict__ bv = z ? kv_b  : qg_b;
    float* __restrict__ o0 = z ? ks : qs;
    float* __restrict__ o1 = z ? vs : gs;

    __shared__ float As[16][36];   // [k][m]
    __shared__ float Bs[16][68];   // [k][n]

    const int tid = threadIdx.x;
    const int tx  = tid & 15;          // 4 n-cols each
    const int ty  = tid >> 4;          // 2 m-rows each
    const int m0  = blockIdx.x << 5;
    const int h   = blockIdx.y;
    const int n0  = h << 6;

    const int arow = tid >> 2;         // valid for tid<128 -> 0..31
    const int acol = (tid & 3) << 2;
    const int brow = tid >> 4;         // 0..15
    const int bcol = (tid & 15) << 2;

    float acc[2][4] = {};
    for (int k0 = 0; k0 < 256; k0 += 16) {
        float4 a4 = {0,0,0,0};
        if (tid < 128)
            a4 = *(const float4*)(A + (size_t)(m0 + arow) * 256 + k0 + acol);
        float4 b4 = *(const float4*)(W + (size_t)(k0 + brow) * 512 + n0 + bcol);
        __syncthreads();
        if (tid < 128) {
            As[acol+0][arow] = a4.x; As[acol+1][arow] = a4.y;
            As[acol+2][arow] = a4.z; As[acol+3][arow] = a4.w;
        }
        *(float4*)&Bs[brow][bcol] = b4;
        __syncthreads();
#pragma unroll
        for (int kk = 0; kk < 16; kk++) {
            const float a0 = As[kk][(ty<<1)+0];
            const float a1 = As[kk][(ty<<1)+1];
            float bw[4]; *(float4*)bw = *(const float4*)&Bs[kk][tx<<2];
#pragma unroll
            for (int j = 0; j < 4; j++) {
                acc[0][j] = fmaf(a0, bw[j], acc[0][j]);
                acc[1][j] = fmaf(a1, bw[j], acc[1][j]);
            }
        }
    }

    const float scale = 0.17677669529663689f;  // 32^-0.5
#pragma unroll
    for (int i = 0; i < 2; i++) {
        const int m = m0 + (ty<<1) + i;
        const size_t base = (((size_t)h << 11) + m) << 5;
#pragma unroll
        for (int j = 0; j < 4; j++) {
            const int nc = (tx<<2) + j;
            float v = acc[i][j] + bv[n0 + nc];
            if (z == 0) {
                if (nc < 32) o0[base + nc] = v * scale;
                else         o1[base + nc - 32] = 1.0f / (1.0f + __expf(-v));
            } else {
                if (nc < 32) o0[base + nc] = v;
                else         o1[base + nc - 32] = v;
            }
        }
    }
}

// ---------------------------------------------------------------------------
// Flash attention with K-split. One block per (32 q-rows, head, k-split).
// Writes unnormalized partial O and (m, l) per q-row; combine pass finishes.
// grid (64, 8, nsplit). LDS 30 KiB -> 5 blocks/CU.
// ---------------------------------------------------------------------------
__global__ __launch_bounds__(256)
void attn_kernel(const float* __restrict__ qs, const float* __restrict__ ks,
                 const float* __restrict__ vs, const float* __restrict__ bias,
                 float* __restrict__ Opart, float* __restrict__ mpart,
                 float* __restrict__ lpart, int ksize)
{
    const int h   = blockIdx.y;
    const int z   = blockIdx.z;
    const int q0  = blockIdx.x << 5;
    const int tid = threadIdx.x;
    const int lg16 = tid & 15;      // logits: 4 k-cols; PV: c-cols lg16, lg16+16
    const int qg   = tid >> 4;      // 16 groups x 2 q-rows
    const int qr0  = qg << 1;

    __shared__ float Qt[32][36];    // [c][qr]
    __shared__ float Kt[32][68];    // [c][kk]
    __shared__ float Vt[32][68];    // [c][kk]
    __shared__ float Ps[32][68];    // [qr][kk]

    // Stage Q (pre-scaled)
    {
        const int qr = tid >> 3;
        const int c0 = (tid & 7) << 2;
        float4 v = *(const float4*)(qs + ((((size_t)h << 11) + q0 + qr) << 5) + c0);
        Qt[c0+0][qr] = v.x; Qt[c0+1][qr] = v.y;
        Qt[c0+2][qr] = v.z; Qt[c0+3][qr] = v.w;
    }

    float mrow[2] = {-1e30f, -1e30f};
    float lrow[2] = {0.f, 0.f};
    float Ob[2][2] = {};
    const size_t bias_base = (((size_t)h) * SEQ + q0) * SEQ;
    const int kbeg  = z * ksize;
    const int ntile = ksize >> 6;

    for (int kt = 0; kt < ntile; kt++) {
        const int k0 = kbeg + (kt << 6);

        // Issue all global loads for this tile before the barrier
        float br[2][4];
#pragma unroll
        for (int i = 0; i < 2; i++)
            *(float4*)br[i] = *(const float4*)(bias + bias_base
                                + (size_t)(qr0 + i) * SEQ + k0 + (lg16 << 2));
        float4 kreg[2], vreg[2];
#pragma unroll
        for (int r = 0; r < 2; r++) {
            const int f  = tid + (r << 8);
            const int kk = f >> 3;
            const int cc = (f & 7) << 2;
            kreg[r] = *(const float4*)(ks + ((((size_t)h << 11) + k0 + kk) << 5) + cc);
            vreg[r] = *(const float4*)(vs + ((((size_t)h << 11) + k0 + kk) << 5) + cc);
        }

        __syncthreads();   // prev PV done with Kt/Vt/Ps; Qt ready (iter 0)
#pragma unroll
        for (int r = 0; r < 2; r++) {
            const int f  = tid + (r << 8);
            const int kk = f >> 3;
            const int cc = (f & 7) << 2;
            Kt[cc+0][kk] = kreg[r].x; Kt[cc+1][kk] = kreg[r].y;
            Kt[cc+2][kk] = kreg[r].z; Kt[cc+3][kk] = kreg[r].w;
            Vt[cc+0][kk] = vreg[r].x; Vt[cc+1][kk] = vreg[r].y;
            Vt[cc+2][kk] = vreg[r].z; Vt[cc+3][kk] = vreg[r].w;
        }
        __syncthreads();

        // Logits 2q x 4k
        float lgt[2][4];
#pragma unroll
        for (int i = 0; i < 2; i++)
#pragma unroll
            for (int j = 0; j < 4; j++) lgt[i][j] = br[i][j];
#pragma unroll
        for (int c = 0; c < 32; c++) {
            float2 qa = *(const float2*)&Qt[c][qr0];
            float ka[4]; *(float4*)ka = *(const float4*)&Kt[c][lg16 << 2];
#pragma unroll
            for (int j = 0; j < 4; j++) {
                lgt[0][j] = fmaf(qa.x, ka[j], lgt[0][j]);
                lgt[1][j] = fmaf(qa.y, ka[j], lgt[1][j]);
            }
        }

        // Online softmax per q-row (reduce across the 16 lanes of this qg)
        float alpha[2];
#pragma unroll
        for (int i = 0; i < 2; i++) {
            float rm = fmaxf(fmaxf(lgt[i][0], lgt[i][1]),
                             fmaxf(lgt[i][2], lgt[i][3]));
#pragma unroll
            for (int off = 1; off < 16; off <<= 1)
                rm = fmaxf(rm, __shfl_xor(rm, off, 16));
            const float mnew = fmaxf(mrow[i], rm);
            alpha[i] = __expf(mrow[i] - mnew);
            mrow[i]  = mnew;
            float rs = 0.f;
#pragma unroll
            for (int j = 0; j < 4; j++) {
                const float p = __expf(lgt[i][j] - mnew);
                lgt[i][j] = p;
                rs += p;
            }
#pragma unroll
            for (int off = 1; off < 16; off <<= 1)
                rs += __shfl_xor(rs, off, 16);
            lrow[i] = lrow[i] * alpha[i] + rs;
            *(float4*)&Ps[qr0 + i][lg16 << 2] = *(float4*)lgt[i];
        }
        __syncthreads();   // Ps visible

        // PV: O[2q][2c] += P @ V^T, c-cols = lg16, lg16+16 (2-way banks: free)
#pragma unroll
        for (int i = 0; i < 2; i++) { Ob[i][0] *= alpha[i]; Ob[i][1] *= alpha[i]; }
#pragma unroll
        for (int k4 = 0; k4 < 16; k4++) {
            float pa[2][4], va[2][4];
            *(float4*)pa[0] = *(const float4*)&Ps[qr0+0][k4 << 2];
            *(float4*)pa[1] = *(const float4*)&Ps[qr0+1][k4 << 2];
            *(float4*)va[0] = *(const float4*)&Vt[lg16     ][k4 << 2];
            *(float4*)va[1] = *(const float4*)&Vt[lg16 + 16][k4 << 2];
#pragma unroll
            for (int i = 0; i < 2; i++)
#pragma unroll
                for (int j = 0; j < 2; j++)
#pragma unroll
                    for (int t = 0; t < 4; t++)
                        Ob[i][j] = fmaf(pa[i][t], va[j][t], Ob[i][j]);
        }
    }

    // Epilogue: unnormalized partials
    const size_t pbase = ((size_t)z * NHEAD + h) << 11;
#pragma unroll
    for (int i = 0; i < 2; i++) {
        const int q = q0 + qr0 + i;
        if (lg16 == 0) {
            mpart[pbase + q] = mrow[i];
            lpart[pbase + q] = lrow[i];
        }
        Opart[((pbase + q) << 5) + lg16     ] = Ob[i][0];
        Opart[((pbase + q) << 5) + lg16 + 16] = Ob[i][1];
    }
}

// ---------------------------------------------------------------------------
// Combine k-split partials + 1/l + sigmoid gating -> att[q][h*32+c]
// ---------------------------------------------------------------------------
__global__ __launch_bounds__(256)
void combine_kernel(const float* __restrict__ Opart, const float* __restrict__ mpart,
                    const float* __restrict__ lpart, const float* __restrict__ gs,
                    float* __restrict__ att, int nsplit)
{
    const int g  = blockIdx.x * 256 + threadIdx.x;  // 131072 total
    const int c4 = g & 7;
    const int q  = (g >> 3) & (SEQ - 1);
    const int h  = g >> 14;

    float M = -1e30f;
    for (int s = 0; s < nsplit; s++)
        M = fmaxf(M, mpart[(((size_t)s * NHEAD + h) << 11) + q]);

    float l = 0.f;
    float4 O = {0.f, 0.f, 0.f, 0.f};
    for (int s = 0; s < nsplit; s++) {
        const size_t base = (((size_t)s * NHEAD + h) << 11) + q;
        const float w = __expf(mpart[base] - M);
        l += w * lpart[base];
        float4 o4 = *(const float4*)(Opart + (base << 5) + (c4 << 2));
        O.x = fmaf(w, o4.x, O.x); O.y = fmaf(w, o4.y, O.y);
        O.z = fmaf(w, o4.z, O.z); O.w = fmaf(w, o4.w, O.w);
    }
    const float inv = 1.0f / l;
    float4 g4 = *(const float4*)(gs + ((((size_t)h << 11) + q) << 5) + (c4 << 2));
    float4 r;
    r.x = O.x * inv * g4.x; r.y = O.y * inv * g4.y;
    r.z = O.z * inv * g4.z; r.w = O.w * inv * g4.w;
    *(float4*)(att + ((size_t)q << 8) + (h << 5) + (c4 << 2)) = r;
}

// ---------------------------------------------------------------------------
// Output projection: out[2048,256] = att[2048,256] @ o_w[256,256] + o_b.
// BM=16, BN=64, BK=16, 256 threads, per-thread 1x4. grid (128, 4).
// ---------------------------------------------------------------------------
__global__ __launch_bounds__(256)
void proj_o_kernel(const float* __restrict__ att, const float* __restrict__ o_w,
                   const float* __restrict__ o_b, float* __restrict__ out)
{
    __shared__ float As[16][20];
    __shared__ float Bs[16][68];

    const int tid = threadIdx.x;
    const int tx  = tid & 15;
    const int ty  = tid >> 4;          // 1 m-row each
    const int m0  = blockIdx.x << 4;
    const int n0  = blockIdx.y << 6;

    const int arow = tid >> 2;         // valid for tid<64 -> 0..15
    const int acol = (tid & 3) << 2;
    const int brow = tid >> 4;
    const int bcol = (tid & 15) << 2;

    float acc[4] = {};
    for (int k0 = 0; k0 < 256; k0 += 16) {
        float4 a4 = {0,0,0,0};
        if (tid < 64)
            a4 = *(const float4*)(att + (size_t)(m0 + arow) * 256 + k0 + acol);
        float4 b4 = *(const float4*)(o_w + (size_t)(k0 + brow) * 256 + n0 + bcol);
        __syncthreads();
        if (tid < 64) {
            As[acol+0][arow] = a4.x; As[acol+1][arow] = a4.y;
            As[acol+2][arow] = a4.z; As[acol+3][arow] = a4.w;
        }
        *(float4*)&Bs[brow][bcol] = b4;
        __syncthreads();
#pragma unroll
        for (int kk = 0; kk < 16; kk++) {
            const float a0 = As[kk][ty];
            float bw[4]; *(float4*)bw = *(const float4*)&Bs[kk][tx<<2];
#pragma unroll
            for (int j = 0; j < 4; j++)
                acc[j] = fmaf(a0, bw[j], acc[j]);
        }
    }

    const int m = m0 + ty;
#pragma unroll
    for (int j = 0; j < 4; j++) {
        const int n = n0 + (tx<<2) + j;
        out[(size_t)m * 256 + n] = acc[j] + o_b[n];
    }
}

// ---------------------------------------------------------------------------
extern "C" void kernel_launch(void* const* d_in, const int* in_sizes, int n_in,
                              void* d_out, int out_size, void* d_ws, size_t ws_size,
                              hipStream_t stream)
{
    const float* q_in  = (const float*)d_in[0];
    const float* kv_in = (const float*)d_in[1];
    const float* bias  = (const float*)d_in[2];
    const float* qg_w  = (const float*)d_in[3];
    const float* kv_w  = (const float*)d_in[4];
    const float* qg_b  = (const float*)d_in[5];
    const float* kv_b  = (const float*)d_in[6];
    const float* o_w   = (const float*)d_in[7];
    const float* o_b   = (const float*)d_in[8];
    float* out = (float*)d_out;

    float* ws = (float*)d_ws;
    const size_t per = (size_t)NHEAD * SEQ * CDIM;   // 524288 floats
    float* qs  = ws;             // q*scale   [h][s][32]
    float* gs  = qs + per;       // sigmoid(g)[h][s][32]
    float* ks  = gs + per;       // k         [h][s][32]
    float* vs  = ks + per;       // v         [h][s][32]
    float* att = vs + per;       // gated out [s][h*32+c]  (= per floats)

    // Pick the largest k-split that fits the workspace (constant across calls)
    int nsplit = 1;
    {
        const size_t cand[3] = {4, 2, 1};
        for (int i = 0; i < 3; i++) {
            size_t ns = cand[i];
            size_t need = (5*per + ns*(per + 2*(size_t)NHEAD*SEQ)) * sizeof(float);
            if (need <= ws_size) { nsplit = (int)ns; break; }
        }
    }
    float* mp = att + per;
    float* lp = mp + (size_t)nsplit * NHEAD * SEQ;
    float* Op = lp + (size_t)nsplit * NHEAD * SEQ;

    hipLaunchKernelGGL(proj_qgkv_kernel, dim3(64, 8, 2), dim3(256), 0, stream,
                       q_in, kv_in, qg_w, kv_w, qg_b, kv_b, qs, gs, ks, vs);
    hipLaunchKernelGGL(attn_kernel, dim3(64, 8, nsplit), dim3(256), 0, stream,
                       qs, ks, vs, bias, Op, mp, lp, SEQ / nsplit);
    hipLaunchKernelGGL(combine_kernel, dim3(512), dim3(256), 0, stream,
                       Op, mp, lp, gs, att, nsplit);
    hipLaunchKernelGGL(proj_o_kernel, dim3(128, 4), dim3(256), 0, stream,
                       att, o_w, o_b, out);
}

// Round 3
// 248.122 us; speedup vs baseline: 1.7900x; 1.3099x over previous
//
#include <hip/hip_runtime.h>
#include <hip/hip_bf16.h>
#include <math.h>

#define SEQ   2048
#define NHEAD 8

typedef __attribute__((ext_vector_type(8))) short bf16x8;
typedef __attribute__((ext_vector_type(4))) short bf16x4;
typedef __attribute__((ext_vector_type(4))) float f32x4;

static __device__ __forceinline__ short f2bf(float f) {
    __hip_bfloat16 h = __float2bfloat16(f);   // RNE
    return *reinterpret_cast<short*>(&h);
}

// ---------------------------------------------------------------------------
// Prep: cast A-matrices to bf16; transpose+cast weights.
// qA[2048][256], kvA[2048][256], wqgT[512][256], wkvT[512][256], owT[256][256]
// ---------------------------------------------------------------------------
__global__ __launch_bounds__(256)
void prep_kernel(const float* __restrict__ q_in, const float* __restrict__ kv_in,
                 const float* __restrict__ qg_w, const float* __restrict__ kv_w,
                 const float* __restrict__ o_w,
                 short* __restrict__ qA, short* __restrict__ kvA,
                 short* __restrict__ wqgT, short* __restrict__ wkvT,
                 short* __restrict__ owT)
{
    const int i = blockIdx.x * 256 + threadIdx.x;
    if (i < 524288) {
        qA[i] = f2bf(q_in[i]);
    } else if (i < 1048576) {
        const int j = i - 524288;
        kvA[j] = f2bf(kv_in[j]);
    } else if (i < 1179648) {
        const int j = i - 1048576, n = j >> 8, k = j & 255;
        wqgT[j] = f2bf(qg_w[k * 512 + n]);
    } else if (i < 1310720) {
        const int j = i - 1179648, n = j >> 8, k = j & 255;
        wkvT[j] = f2bf(kv_w[k * 512 + n]);
    } else if (i < 1376256) {
        const int j = i - 1310720, n = j >> 8, k = j & 255;
        owT[j] = f2bf(o_w[k * 256 + n]);
    }
}

// ---------------------------------------------------------------------------
// QG/KV projection, MFMA. z=0: QG -> qs(bf16, *scale), gs(f32, sigmoid);
// z=1: KV -> ks(bf16), vT(bf16, transposed [h][c][s]).
// Wave tile 16m x 32n over K=256; block = 4 waves on m. grid (32,16,2).
// ---------------------------------------------------------------------------
__global__ __launch_bounds__(256)
void proj_qgkv_kernel(const short* __restrict__ qA, const short* __restrict__ kvA,
                      const short* __restrict__ wqgT, const short* __restrict__ wkvT,
                      const float* __restrict__ qg_b, const float* __restrict__ kv_b,
                      short* __restrict__ qs, float* __restrict__ gs,
                      short* __restrict__ ks, short* __restrict__ vT)
{
    const int z = blockIdx.z;
    const short* __restrict__ A  = z ? kvA  : qA;
    const short* __restrict__ W  = z ? wkvT : wqgT;
    const float* __restrict__ bv = z ? kv_b : qg_b;

    const int tid = threadIdx.x;
    const int wq = tid >> 6, lane = tid & 63;
    const int ln = lane & 15, quad = lane >> 4;
    const int m0 = blockIdx.x << 6;
    const int n0 = blockIdx.y << 5;

    f32x4 acc[2];
#pragma unroll
    for (int nt = 0; nt < 2; nt++) {
        const float b = bv[n0 + (nt << 4) + ln];
        acc[nt] = (f32x4){b, b, b, b};
    }

    const short* ap = A + (size_t)(m0 + (wq << 4) + ln) * 256 + (quad << 3);
    for (int k8 = 0; k8 < 8; k8++) {
        bf16x8 a = *(const bf16x8*)(ap + k8 * 32);
#pragma unroll
        for (int nt = 0; nt < 2; nt++) {
            bf16x8 b = *(const bf16x8*)(W + (size_t)(n0 + (nt << 4) + ln) * 256
                                          + k8 * 32 + (quad << 3));
            acc[nt] = __builtin_amdgcn_mfma_f32_16x16x32_bf16(a, b, acc[nt], 0, 0, 0);
        }
    }

    const float scale = 0.17677669529663689f;  // 32^-0.5
#pragma unroll
    for (int nt = 0; nt < 2; nt++) {
        const int n = n0 + (nt << 4) + ln;
        const int h = n >> 6, c2 = n & 63;
#pragma unroll
        for (int r = 0; r < 4; r++) {
            const int m = m0 + (wq << 4) + (quad << 2) + r;
            const float v = acc[nt][r];
            if (z == 0) {
                if (c2 < 32) qs[(((h << 11) + m) << 5) + c2] = f2bf(v * scale);
                else gs[(((h << 11) + m) << 5) + (c2 - 32)] = 1.0f / (1.0f + __expf(-v));
            } else {
                if (c2 < 32) ks[(((h << 11) + m) << 5) + c2] = f2bf(v);
                else vT[(((h << 5) + (c2 - 32)) << 11) + m] = f2bf(v);
            }
        }
    }
}

// ---------------------------------------------------------------------------
// MFMA flash attention, barrier-free. S^T = K*Q^T (bias as C-operand),
// online softmax per-lane, PV via quad-local k-permutation (no P shuffle/LDS).
// grid (32 qtiles, 8 heads, nsplit). Block = 4 waves, wave = 16 q-rows.
// Partials: Opart unnormalized, mpart in log2-domain, lpart linear.
// ---------------------------------------------------------------------------
__global__ __launch_bounds__(256)
void attn_kernel(const short* __restrict__ qs, const short* __restrict__ ks,
                 const short* __restrict__ vT, const float* __restrict__ bias,
                 float* __restrict__ Opart, float* __restrict__ mpart,
                 float* __restrict__ lpart, int ksize)
{
    const int h = blockIdx.y, z = blockIdx.z;
    const int q0 = blockIdx.x << 6;
    const int tid = threadIdx.x;
    const int wq = tid >> 6, lane = tid & 63;
    const int ln = lane & 15, quad = lane >> 4;

    __shared__ float blds[4][16][68];   // wave-private bias tiles (padded)

    const int qrow = q0 + (wq << 4) + ln;
    const bf16x8 qf = *(const bf16x8*)(qs + (((size_t)(h << 11) + qrow) << 5) + (quad << 3));

    const float L2E = 1.44269504088896f;
    float ml2 = -1e30f, l = 0.f;
    f32x4 O0 = {0, 0, 0, 0}, O1 = {0, 0, 0, 0};

    const int kbeg = z * ksize;
    const int ntile = ksize >> 6;
    const size_t bias_row0 = ((size_t)h * SEQ + q0 + (wq << 4)) * SEQ;

    for (int kt = 0; kt < ntile; kt++) {
        const int k0 = kbeg + (kt << 6);

        // --- stage bias tile (coalesced global -> wave-private LDS) ---
#pragma unroll
        for (int p = 0; p < 4; p++) {
            const int row = (quad << 2) + p;
            float4 b4 = *(const float4*)(bias + bias_row0 + (size_t)row * SEQ
                                         + k0 + (ln << 2));
            *(float4*)&blds[wq][row][ln << 2] = b4;
        }
        // --- K fragments (direct global bf16, 16B) ---
        bf16x8 kf[4];
#pragma unroll
        for (int mt = 0; mt < 4; mt++)
            kf[mt] = *(const bf16x8*)(ks + (((size_t)(h << 11) + k0 + (mt << 4) + ln) << 5)
                                         + (quad << 3));
        // --- V fragments (direct global bf16 from vT, 8B halves) ---
        bf16x4 vh[2][2][2];
#pragma unroll
        for (int cm = 0; cm < 2; cm++) {
            const size_t vb = (((size_t)(h << 5) + (cm << 4) + ln) << 11) + k0 + (quad << 2);
#pragma unroll
            for (int kc = 0; kc < 2; kc++)
#pragma unroll
                for (int hf = 0; hf < 2; hf++)
                    vh[cm][kc][hf] = *(const bf16x4*)(vT + vb + (kc << 5) + (hf << 4));
        }

        // --- QK^T: S^T[kcol][q], bias as C-init (read back in C-layout) ---
        f32x4 S[4];
#pragma unroll
        for (int mt = 0; mt < 4; mt++) {
            f32x4 c = *(const f32x4*)&blds[wq][ln][(mt << 4) + (quad << 2)];
            S[mt] = __builtin_amdgcn_mfma_f32_16x16x32_bf16(kf[mt], qf, c, 0, 0, 0);
        }

        // --- online softmax (per-lane q; reduce across quads only) ---
        float smax = S[0][0];
#pragma unroll
        for (int mt = 0; mt < 4; mt++)
#pragma unroll
            for (int r = 0; r < 4; r++) smax = fmaxf(smax, S[mt][r]);
        smax = fmaxf(smax, __shfl_xor(smax, 16));
        smax = fmaxf(smax, __shfl_xor(smax, 32));
        const float mnew = fmaxf(ml2, smax * L2E);
        const float alpha = exp2f(ml2 - mnew);
        ml2 = mnew;

        float pr[4][4];
        float rs = 0.f;
#pragma unroll
        for (int mt = 0; mt < 4; mt++)
#pragma unroll
            for (int r = 0; r < 4; r++) {
                const float p = exp2f(fmaf(S[mt][r], L2E, -mnew));
                pr[mt][r] = p;
                rs += p;
            }
        rs += __shfl_xor(rs, 16);
        rs += __shfl_xor(rs, 32);
        l = l * alpha + rs;

        // --- pack P into PV B-fragments (quad-local k-permutation: no shuffle) ---
        short pb[4][4];
#pragma unroll
        for (int mt = 0; mt < 4; mt++)
#pragma unroll
            for (int r = 0; r < 4; r++) pb[mt][r] = f2bf(pr[mt][r]);
        bf16x8 P0 = {pb[0][0], pb[0][1], pb[0][2], pb[0][3],
                     pb[1][0], pb[1][1], pb[1][2], pb[1][3]};
        bf16x8 P1 = {pb[2][0], pb[2][1], pb[2][2], pb[2][3],
                     pb[3][0], pb[3][1], pb[3][2], pb[3][3]};

        // --- PV: O^T[c][q] accumulate (rescale by alpha first) ---
        O0 *= alpha;
        O1 *= alpha;
#pragma unroll
        for (int kc = 0; kc < 2; kc++) {
            const bf16x8 P = kc ? P1 : P0;
            bf16x8 va0 = __builtin_shufflevector(vh[0][kc][0], vh[0][kc][1],
                                                 0, 1, 2, 3, 4, 5, 6, 7);
            bf16x8 va1 = __builtin_shufflevector(vh[1][kc][0], vh[1][kc][1],
                                                 0, 1, 2, 3, 4, 5, 6, 7);
            O0 = __builtin_amdgcn_mfma_f32_16x16x32_bf16(va0, P, O0, 0, 0, 0);
            O1 = __builtin_amdgcn_mfma_f32_16x16x32_bf16(va1, P, O1, 0, 0, 0);
        }
    }

    // --- epilogue: unnormalized partials ---
    const size_t pb_ = (((size_t)(z * NHEAD + h)) << 11) + qrow;
    if (quad == 0) { mpart[pb_] = ml2; lpart[pb_] = l; }
    float* op = Opart + (pb_ << 5);
#pragma unroll
    for (int r = 0; r < 4; r++) {
        op[(quad << 2) + r]      = O0[r];
        op[16 + (quad << 2) + r] = O1[r];
    }
}

// ---------------------------------------------------------------------------
// Combine k-split partials + 1/l + sigmoid gate -> att bf16 [s][h*32+c]
// (mpart is in log2 domain -> exp2f weights)
// ---------------------------------------------------------------------------
__global__ __launch_bounds__(256)
void combine_kernel(const float* __restrict__ Opart, const float* __restrict__ mpart,
                    const float* __restrict__ lpart, const float* __restrict__ gs,
                    short* __restrict__ att, int nsplit)
{
    const int g  = blockIdx.x * 256 + threadIdx.x;  // 131072
    const int c4 = g & 7;
    const int q  = (g >> 3) & (SEQ - 1);
    const int h  = g >> 14;

    float M = -1e30f;
    for (int s = 0; s < nsplit; s++)
        M = fmaxf(M, mpart[(((size_t)s * NHEAD + h) << 11) + q]);

    float l = 0.f;
    float4 O = {0.f, 0.f, 0.f, 0.f};
    for (int s = 0; s < nsplit; s++) {
        const size_t base = (((size_t)s * NHEAD + h) << 11) + q;
        const float w = exp2f(mpart[base] - M);
        l += w * lpart[base];
        float4 o4 = *(const float4*)(Opart + (base << 5) + (c4 << 2));
        O.x = fmaf(w, o4.x, O.x); O.y = fmaf(w, o4.y, O.y);
        O.z = fmaf(w, o4.z, O.z); O.w = fmaf(w, o4.w, O.w);
    }
    const float inv = 1.0f / l;
    float4 g4 = *(const float4*)(gs + ((((size_t)h << 11) + q) << 5) + (c4 << 2));
    bf16x4 r;
    r[0] = f2bf(O.x * inv * g4.x); r[1] = f2bf(O.y * inv * g4.y);
    r[2] = f2bf(O.z * inv * g4.z); r[3] = f2bf(O.w * inv * g4.w);
    *(bf16x4*)(att + ((size_t)q << 8) + (h << 5) + (c4 << 2)) = r;
}

// ---------------------------------------------------------------------------
// Output projection, MFMA: out[2048,256] = att(bf16) @ o_w + o_b.
// Wave tile 16m x 16n over K=256; block = 4 waves on m. grid (32,16).
// ---------------------------------------------------------------------------
__global__ __launch_bounds__(256)
void proj_o_kernel(const short* __restrict__ att, const short* __restrict__ owT,
                   const float* __restrict__ o_b, float* __restrict__ out)
{
    const int tid = threadIdx.x;
    const int wq = tid >> 6, lane = tid & 63;
    const int ln = lane & 15, quad = lane >> 4;
    const int m0 = blockIdx.x << 6;
    const int n0 = blockIdx.y << 4;

    const int n = n0 + ln;
    const float b = o_b[n];
    f32x4 acc = (f32x4){b, b, b, b};

    const short* ap = att + (size_t)(m0 + (wq << 4) + ln) * 256 + (quad << 3);
    const short* bp = owT + (size_t)n * 256 + (quad << 3);
    for (int k8 = 0; k8 < 8; k8++) {
        bf16x8 a = *(const bf16x8*)(ap + k8 * 32);
        bf16x8 w = *(const bf16x8*)(bp + k8 * 32);
        acc = __builtin_amdgcn_mfma_f32_16x16x32_bf16(a, w, acc, 0, 0, 0);
    }
#pragma unroll
    for (int r = 0; r < 4; r++) {
        const int m = m0 + (wq << 4) + (quad << 2) + r;
        out[(size_t)m * 256 + n] = acc[r];
    }
}

// ---------------------------------------------------------------------------
extern "C" void kernel_launch(void* const* d_in, const int* in_sizes, int n_in,
                              void* d_out, int out_size, void* d_ws, size_t ws_size,
                              hipStream_t stream)
{
    const float* q_in  = (const float*)d_in[0];
    const float* kv_in = (const float*)d_in[1];
    const float* bias  = (const float*)d_in[2];
    const float* qg_w  = (const float*)d_in[3];
    const float* kv_w  = (const float*)d_in[4];
    const float* qg_b  = (const float*)d_in[5];
    const float* kv_b  = (const float*)d_in[6];
    const float* o_w   = (const float*)d_in[7];
    const float* o_b   = (const float*)d_in[8];
    float* out = (float*)d_out;

    // Workspace layout (bytes)
    char* p = (char*)d_ws;
    short* qs   = (short*)p; p += 1048576;   // bf16 [h][s][32], pre-scaled
    short* ksb  = (short*)p; p += 1048576;   // bf16 [h][s][32]
    short* vTb  = (short*)p; p += 1048576;   // bf16 [h][c][s]
    short* attb = (short*)p; p += 1048576;   // bf16 [s][h*32+c]
    short* qA   = (short*)p; p += 1048576;   // bf16 [2048][256]
    short* kvA  = (short*)p; p += 1048576;   // bf16 [2048][256]
    short* wqgT = (short*)p; p += 262144;    // bf16 [512][256]
    short* wkvT = (short*)p; p += 262144;    // bf16 [512][256]
    short* owT  = (short*)p; p += 131072;    // bf16 [256][256]
    float* gs   = (float*)p; p += 2097152;   // f32  [h][s][32] sigmoid(g)

    // nsplit from ws_size only (constant across calls; graph-safe)
    const size_t fixed = (size_t)(p - (char*)d_ws);
    int nsplit = 1;
    {
        const int cand[3] = {4, 2, 1};
        for (int i = 0; i < 3; i++) {
            size_t ns = (size_t)cand[i];
            if (fixed + ns * (2097152 + 131072) <= ws_size) { nsplit = cand[i]; break; }
        }
    }
    float* mp = (float*)p;                      // [ns][8][2048]
    float* lp = mp + (size_t)nsplit * NHEAD * SEQ;
    float* Op = lp + (size_t)nsplit * NHEAD * SEQ;   // [ns][8][2048][32]

    hipLaunchKernelGGL(prep_kernel, dim3(5376), dim3(256), 0, stream,
                       q_in, kv_in, qg_w, kv_w, o_w, qA, kvA, wqgT, wkvT, owT);
    hipLaunchKernelGGL(proj_qgkv_kernel, dim3(32, 16, 2), dim3(256), 0, stream,
                       qA, kvA, wqgT, wkvT, qg_b, kv_b, qs, gs, ksb, vTb);
    hipLaunchKernelGGL(attn_kernel, dim3(32, NHEAD, nsplit), dim3(256), 0, stream,
                       qs, ksb, vTb, bias, Op, mp, lp, SEQ / nsplit);
    hipLaunchKernelGGL(combine_kernel, dim3(512), dim3(256), 0, stream,
                       Op, mp, lp, gs, attb, nsplit);
    hipLaunchKernelGGL(proj_o_kernel, dim3(32, 16), dim3(256), 0, stream,
                       attb, owT, o_b, out);
}